// Round 1
// baseline (97.682 us; speedup 1.0000x reference)
//
#include <hip/hip_runtime.h>
#include <cstdint>
#include <cstddef>

#define LSEQ 1024
#define NH   16
#define NX   8

// float -> bf16 with round-to-nearest-even
__device__ __forceinline__ uint32_t f2bf(float f) {
    uint32_t u = __float_as_uint(f);
    u += 0x7fffu + ((u >> 16) & 1u);
    return u >> 16;
}
__device__ __forceinline__ float bflo(uint32_t w) { return __uint_as_float(w << 16); }
__device__ __forceinline__ float bfhi(uint32_t w) { return __uint_as_float(w & 0xffff0000u); }

__global__ __launch_bounds__(256, 1)
void attn_fused_kernel(const float* __restrict__ x, const float* __restrict__ pos,
                       const float* __restrict__ Wq, const float* __restrict__ Wk,
                       const float* __restrict__ Wv, const float* __restrict__ Wo,
                       float* __restrict__ out) {
    // 64 KB static LDS. q/k bf16 tiles; small post-phase-B arrays aliased on top
    // (safe: only touched after a __syncthreads() following the last q/k read).
    __shared__ __align__(16) char smem_raw[65536];
    uint16_t* q_lds = (uint16_t*)smem_raw;             // [1024][16] bf16
    uint16_t* k_lds = (uint16_t*)(smem_raw + 32768);   // [1024][16] bf16
    float* scorebuf = (float*)smem_raw;                // [4][16][16] partials
    float* attn_s   = (float*)(smem_raw + 4096);       // [16][16]
    float* M_s      = (float*)(smem_raw + 5120);       // [16][16]
    float* weff_s   = (float*)(smem_raw + 6144);       // [16][8]

    const int tid = threadIdx.x;
    const int b   = blockIdx.x;
    const float* xb = x   + (size_t)b * LSEQ * NX;
    const float* pb = pos + (size_t)b * LSEQ;

    // ================= Phase A: q,k = x*W^T + P(pos) -> LDS (bf16) ============
    // wave dg (=tid>>6) owns channels 4dg..4dg+3; lane covers l = p*64 + lidx
    {
        const int dg   = tid >> 6;
        const int lidx = tid & 63;
        float wq[4][8], wk[4][8];
        #pragma unroll
        for (int r = 0; r < 4; ++r) {
            const float4 a0 = *(const float4*)(Wq + (4 * dg + r) * 8);
            const float4 a1 = *(const float4*)(Wq + (4 * dg + r) * 8 + 4);
            const float4 b0 = *(const float4*)(Wk + (4 * dg + r) * 8);
            const float4 b1 = *(const float4*)(Wk + (4 * dg + r) * 8 + 4);
            wq[r][0]=a0.x; wq[r][1]=a0.y; wq[r][2]=a0.z; wq[r][3]=a0.w;
            wq[r][4]=a1.x; wq[r][5]=a1.y; wq[r][6]=a1.z; wq[r][7]=a1.w;
            wk[r][0]=b0.x; wk[r][1]=b0.y; wk[r][2]=b0.z; wk[r][3]=b0.w;
            wk[r][4]=b1.x; wk[r][5]=b1.y; wk[r][6]=b1.z; wk[r][7]=b1.w;
        }
        const float f0 = (float)(2 * dg + 1);   // sin/cos multiplier, pair 2dg
        const float f1 = (float)(2 * dg + 2);   // pair 2dg+1
        for (int p = 0; p < 16; ++p) {
            const int l = p * 64 + lidx;
            const float4 xa = *(const float4*)(xb + (size_t)l * 8);
            const float4 xc = *(const float4*)(xb + (size_t)l * 8 + 4);
            const float pv = pb[l];
            float pe[4];
            pe[0] = sinpif(pv * f0); pe[1] = cospif(pv * f0);
            pe[2] = sinpif(pv * f1); pe[3] = cospif(pv * f1);
            float qv[4], kv[4];
            #pragma unroll
            for (int r = 0; r < 4; ++r) {
                qv[r] = xa.x*wq[r][0] + xa.y*wq[r][1] + xa.z*wq[r][2] + xa.w*wq[r][3]
                      + xc.x*wq[r][4] + xc.y*wq[r][5] + xc.z*wq[r][6] + xc.w*wq[r][7] + pe[r];
                kv[r] = xa.x*wk[r][0] + xa.y*wk[r][1] + xa.z*wk[r][2] + xa.w*wk[r][3]
                      + xc.x*wk[r][4] + xc.y*wk[r][5] + xc.z*wk[r][6] + xc.w*wk[r][7] + pe[r];
            }
            uint2 qp, kp;
            qp.x = f2bf(qv[0]) | (f2bf(qv[1]) << 16);
            qp.y = f2bf(qv[2]) | (f2bf(qv[3]) << 16);
            kp.x = f2bf(kv[0]) | (f2bf(kv[1]) << 16);
            kp.y = f2bf(kv[2]) | (f2bf(kv[3]) << 16);
            *(uint2*)(q_lds + (size_t)l * 16 + 4 * dg) = qp;
            *(uint2*)(k_lds + (size_t)l * 16 + 4 * dg) = kp;
        }
    }
    __syncthreads();

    // ============ Phase B: score[d][e] = sum_l q[l,d]*k[l,e] ==================
    // thread tid -> (lg = tid>>4, dt = (tid>>2)&3, et = tid&3); 4x4 tile, l = 16i+lg
    {
        const int lg = tid >> 4;
        const int dt = (tid >> 2) & 3;
        const int et = tid & 3;
        float acc[4][4];
        #pragma unroll
        for (int i = 0; i < 4; ++i)
            #pragma unroll
            for (int j = 0; j < 4; ++j) acc[i][j] = 0.f;

        const uint16_t* qp = q_lds + lg * 16 + dt * 4;
        const uint16_t* kp = k_lds + lg * 16 + et * 4;
        #pragma unroll 4
        for (int i = 0; i < 64; ++i) {
            const uint2 qw = *(const uint2*)(qp + i * 256);
            const uint2 kw = *(const uint2*)(kp + i * 256);
            const float q0 = bflo(qw.x), q1 = bfhi(qw.x), q2 = bflo(qw.y), q3 = bfhi(qw.y);
            const float k0 = bflo(kw.x), k1 = bfhi(kw.x), k2 = bflo(kw.y), k3 = bfhi(kw.y);
            acc[0][0] += q0*k0; acc[0][1] += q0*k1; acc[0][2] += q0*k2; acc[0][3] += q0*k3;
            acc[1][0] += q1*k0; acc[1][1] += q1*k1; acc[1][2] += q1*k2; acc[1][3] += q1*k3;
            acc[2][0] += q2*k0; acc[2][1] += q2*k1; acc[2][2] += q2*k2; acc[2][3] += q2*k3;
            acc[3][0] += q3*k0; acc[3][1] += q3*k1; acc[3][2] += q3*k2; acc[3][3] += q3*k3;
        }
        // in-wave reduction over the 4 lg values living in one wave (lanes ^16, ^32)
        #pragma unroll
        for (int di = 0; di < 4; ++di)
            #pragma unroll
            for (int ei = 0; ei < 4; ++ei) {
                acc[di][ei] += __shfl_xor(acc[di][ei], 16);
                acc[di][ei] += __shfl_xor(acc[di][ei], 32);
            }
        __syncthreads();   // all q/k reads done -> safe to alias LDS
        const int lane = tid & 63;
        const int w    = tid >> 6;
        if (lane < 16) {
            #pragma unroll
            for (int di = 0; di < 4; ++di)
                #pragma unroll
                for (int ei = 0; ei < 4; ++ei)
                    scorebuf[w * 256 + (dt * 4 + di) * 16 + (et * 4 + ei)] = acc[di][ei];
        }
    }
    __syncthreads();

    // ============ softmax over e, then M = Wo*attn, W_eff = M*Wv ==============
    {
        const int e = tid & 15;
        float s = scorebuf[tid] + scorebuf[256 + tid] + scorebuf[512 + tid] + scorebuf[768 + tid];
        s *= 0.03125f;                       // 1/sqrt(1024)
        float mx = s;
        #pragma unroll
        for (int m = 1; m < 16; m <<= 1) mx = fmaxf(mx, __shfl_xor(mx, m));
        const float ex = __expf(s - mx);
        float sum = ex;
        #pragma unroll
        for (int m = 1; m < 16; m <<= 1) sum += __shfl_xor(sum, m);
        attn_s[tid] = ex / sum;
        __syncthreads();

        const int h = tid >> 4;
        float acc = 0.f;
        #pragma unroll
        for (int d = 0; d < 16; ++d) acc += Wo[h * 16 + d] * attn_s[d * 16 + e];
        M_s[h * 16 + e] = acc;
        __syncthreads();

        if (tid < 128) {
            const int hh = tid >> 3, xc = tid & 7;
            float wv = 0.f;
            #pragma unroll
            for (int ee = 0; ee < 16; ++ee) wv += M_s[hh * 16 + ee] * Wv[ee * 8 + xc];
            weff_s[hh * 8 + xc] = wv;
        }
    }
    __syncthreads();

    // ============ Phase C: out[l][h] = sum_x x[l][x] * W_eff[h][x] ============
    {
        float xr[4][8];
        #pragma unroll
        for (int r = 0; r < 4; ++r) {
            const int l = tid + 256 * r;
            const float4 a = *(const float4*)(xb + (size_t)l * 8);
            const float4 c = *(const float4*)(xb + (size_t)l * 8 + 4);
            xr[r][0]=a.x; xr[r][1]=a.y; xr[r][2]=a.z; xr[r][3]=a.w;
            xr[r][4]=c.x; xr[r][5]=c.y; xr[r][6]=c.z; xr[r][7]=c.w;
        }
        float o[4][16];
        #pragma unroll
        for (int h = 0; h < 16; ++h) {
            const float4 wA = *(const float4*)(weff_s + h * 8);
            const float4 wB = *(const float4*)(weff_s + h * 8 + 4);
            #pragma unroll
            for (int r = 0; r < 4; ++r) {
                o[r][h] = xr[r][0]*wA.x + xr[r][1]*wA.y + xr[r][2]*wA.z + xr[r][3]*wA.w
                        + xr[r][4]*wB.x + xr[r][5]*wB.y + xr[r][6]*wB.z + xr[r][7]*wB.w;
            }
        }
        #pragma unroll
        for (int r = 0; r < 4; ++r) {
            const size_t base = ((size_t)b * LSEQ + tid + 256 * r) * NH;
            #pragma unroll
            for (int g = 0; g < 4; ++g) {
                *(float4*)(out + base + g * 4) =
                    make_float4(o[r][g*4+0], o[r][g*4+1], o[r][g*4+2], o[r][g*4+3]);
            }
        }
    }
}

extern "C" void kernel_launch(void* const* d_in, const int* in_sizes, int n_in,
                              void* d_out, int out_size, void* d_ws, size_t ws_size,
                              hipStream_t stream) {
    const float* x   = (const float*)d_in[0];
    const float* pos = (const float*)d_in[1];
    const float* Wq  = (const float*)d_in[2];
    const float* Wk  = (const float*)d_in[3];
    const float* Wv  = (const float*)d_in[4];
    const float* Wo  = (const float*)d_in[5];
    float* out = (float*)d_out;
    const int B = in_sizes[1] / LSEQ;   // pos has B*L elements
    attn_fused_kernel<<<B, 256, 0, stream>>>(x, pos, Wq, Wk, Wv, Wo, out);
}